// Round 8
// baseline (1729.192 us; speedup 1.0000x reference)
//
#include <hip/hip_runtime.h>
#include <hip/hip_bf16.h>
#include <math.h>

#define HID 256
#define HEADS 8
#define KP0 512
#define EPB 16384      // edges per block in hist/scatter passes
#define NBMAX 1024     // max buckets (N/128 = 782 here)
#define FKG 16         // node-groups per final_kernel block (Wf staged once per block)

typedef __attribute__((ext_vector_type(8))) short short8;
typedef __attribute__((ext_vector_type(4))) float floatx4;
typedef __attribute__((ext_vector_type(4))) unsigned uintx4;

__device__ __forceinline__ void gl_lds16(const void* g, void* l) {
  __builtin_amdgcn_global_load_lds(
      (const __attribute__((address_space(1))) void*)g,
      (__attribute__((address_space(3))) void*)l, 16, 0, 0);
}

__device__ __forceinline__ float blo(unsigned u) { return __uint_as_float(u << 16); }
__device__ __forceinline__ float bhi(unsigned u) { return __uint_as_float(u & 0xffff0000u); }

__device__ __forceinline__ void acc8(float* acc, uintx4 g, float w) {
  acc[0] += w * blo(g[0]); acc[1] += w * bhi(g[0]);
  acc[2] += w * blo(g[1]); acc[3] += w * bhi(g[1]);
  acc[4] += w * blo(g[2]); acc[5] += w * bhi(g[2]);
  acc[6] += w * blo(g[3]); acc[7] += w * bhi(g[3]);
}

// ---------------- contention-free bucketed CSR build ----------------

__global__ __launch_bounds__(256) void edge_hist_kernel(const int* __restrict__ ei,
    int* __restrict__ F, int E, int Etot, int NB, int NBLK) {
  __shared__ int hist[NBMAX];
  int blk = blockIdx.x, t = threadIdx.x;
  for (int i = t; i < NBMAX; i += 256) hist[i] = 0;
  __syncthreads();
  int base = blk * EPB;
  int lim = min(EPB, Etot - base);
  for (int i = t; i < lim; i += 256) {
    int idx = base + i;
    int d = (idx < E) ? ei[E + idx] : (idx - E);
    atomicAdd(&hist[d >> 7], 1);
  }
  __syncthreads();
  for (int b = t; b < NB; b += 256) F[b * NBLK + blk] = hist[b];
}

__global__ __launch_bounds__(256) void scan_part_kernel(const int* __restrict__ F,
    int* __restrict__ bsum, int L) {
  __shared__ int ws[4];
  int blk = blockIdx.x, t = threadIdx.x;
  int base = blk * 1024 + t * 4;
  int s = 0;
  if (base + 3 < L) {
    int4 v = *(const int4*)(F + base);
    s = v.x + v.y + v.z + v.w;
  } else {
    for (int i = 0; i < 4; ++i) if (base + i < L) s += F[base + i];
  }
#pragma unroll
  for (int off = 1; off < 64; off <<= 1) s += __shfl_xor(s, off);
  if ((t & 63) == 0) ws[t >> 6] = s;
  __syncthreads();
  if (t == 0) bsum[blk] = ws[0] + ws[1] + ws[2] + ws[3];
}

__global__ __launch_bounds__(256) void scan_bsum_kernel(const int* __restrict__ bsum,
    int* __restrict__ bb, int* __restrict__ S, int NBS, int L) {
  __shared__ int ps[256];
  int t = threadIdx.x;
  int v = (t < NBS) ? bsum[t] : 0;
  ps[t] = v;
  __syncthreads();
  for (int off = 1; off < 256; off <<= 1) {
    int add = (t >= off) ? ps[t - off] : 0;
    __syncthreads();
    ps[t] += add;
    __syncthreads();
  }
  if (t < NBS) bb[t] = (t == 0) ? 0 : ps[t - 1];
  if (t == 255) S[L] = ps[255];
}

__global__ __launch_bounds__(256) void scan_apply_kernel(const int* __restrict__ F,
    const int* __restrict__ bb, int* __restrict__ S, int L) {
  __shared__ int ps[256];
  int blk = blockIdx.x, t = threadIdx.x;
  int base = blk * 1024 + t * 4;
  int v0 = 0, v1 = 0, v2 = 0, v3 = 0;
  if (base + 3 < L) {
    int4 w = *(const int4*)(F + base);
    v0 = w.x; v1 = w.y; v2 = w.z; v3 = w.w;
  } else {
    if (base + 0 < L) v0 = F[base + 0];
    if (base + 1 < L) v1 = F[base + 1];
    if (base + 2 < L) v2 = F[base + 2];
    if (base + 3 < L) v3 = F[base + 3];
  }
  ps[t] = v0 + v1 + v2 + v3;
  __syncthreads();
  for (int off = 1; off < 256; off <<= 1) {
    int add = (t >= off) ? ps[t - off] : 0;
    __syncthreads();
    ps[t] += add;
    __syncthreads();
  }
  int run = bb[blk] + ((t == 0) ? 0 : ps[t - 1]);
  if (base + 0 < L) S[base + 0] = run; run += v0;
  if (base + 1 < L) S[base + 1] = run; run += v1;
  if (base + 2 < L) S[base + 2] = run; run += v2;
  if (base + 3 < L) S[base + 3] = run;
}

__global__ __launch_bounds__(256) void edge_scatter_kernel(const int* __restrict__ ei,
    const int* __restrict__ S, unsigned* __restrict__ stag, int E, int Etot,
    int NB, int NBLK) {
  __shared__ int cur[NBMAX];
  int blk = blockIdx.x, t = threadIdx.x;
  for (int b = t; b < NB; b += 256) cur[b] = S[b * NBLK + blk];
  __syncthreads();
  int base = blk * EPB;
  int lim = min(EPB, Etot - base);
  for (int i = t; i < lim; i += 256) {
    int idx = base + i;
    int s, d;
    if (idx < E) { s = ei[idx]; d = ei[E + idx]; }
    else { s = idx - E; d = s; }
    int pos = atomicAdd(&cur[d >> 7], 1);
    stag[pos] = ((unsigned)(d & 127) << 17) | (unsigned)s;
  }
}

__global__ __launch_bounds__(256) void bucket_build_kernel(const unsigned* __restrict__ stag,
    const int* __restrict__ S, int NBLK,
    int* __restrict__ rowptr, int* __restrict__ csr_src, int N) {
  __shared__ int deg[128], pfx[128], cur[128];
  int b = blockIdx.x;
  int t = threadIdx.x;
  int gbase = S[(size_t)b * NBLK];
  int gend = S[(size_t)(b + 1) * NBLK];
  int cnt = gend - gbase;
  int node0 = b << 7;
  int nn = min(128, N - node0);
  if (t < 128) deg[t] = 0;
  __syncthreads();
  const unsigned* sb = stag + gbase;
  for (int i = t; i < cnt; i += 256) atomicAdd(&deg[sb[i] >> 17], 1);
  __syncthreads();
  if (t == 0) {
    int run = 0;
#pragma unroll 8
    for (int i = 0; i < 128; ++i) { pfx[i] = run; run += deg[i]; }
  }
  __syncthreads();
  if (t < 128) cur[t] = pfx[t];
  if (t < nn) rowptr[node0 + t] = gbase + pfx[t];
  if (b == (int)gridDim.x - 1 && t == 0) rowptr[N] = gbase + cnt;
  __syncthreads();
  for (int i = t; i < cnt; i += 256) {
    unsigned v = sb[i];
    int dl = v >> 17;
    int pos = gbase + atomicAdd(&cur[dl], 1);
    csr_src[pos] = (int)(v & 0x1ffff);
  }
}

// ---------------- input conversions ----------------

__global__ __launch_bounds__(256) void conv_x_kernel(const float* __restrict__ x,
    __hip_bfloat16* __restrict__ xb, int M, int K) {
  long idx = (long)blockIdx.x * 256 + threadIdx.x;
  if (idx >= (long)M * (KP0 / 8)) return;
  int n = (int)(idx >> 6);
  int k0 = ((int)idx & 63) * 8;
  const float* xr = x + (size_t)n * K;
  float4 a = {0.f, 0.f, 0.f, 0.f}, b = {0.f, 0.f, 0.f, 0.f};
  if (k0 + 3 < K) a = *(const float4*)(xr + k0);
  else {
    if (k0 + 0 < K) a.x = xr[k0 + 0];
    if (k0 + 1 < K) a.y = xr[k0 + 1];
    if (k0 + 2 < K) a.z = xr[k0 + 2];
    if (k0 + 3 < K) a.w = xr[k0 + 3];
  }
  if (k0 + 7 < K) b = *(const float4*)(xr + k0 + 4);
  else {
    if (k0 + 4 < K) b.x = xr[k0 + 4];
    if (k0 + 5 < K) b.y = xr[k0 + 5];
    if (k0 + 6 < K) b.z = xr[k0 + 6];
    if (k0 + 7 < K) b.w = xr[k0 + 7];
  }
  union { short8 v; __hip_bfloat16 h[8]; } o;
  o.h[0] = __float2bfloat16(a.x); o.h[1] = __float2bfloat16(a.y);
  o.h[2] = __float2bfloat16(a.z); o.h[3] = __float2bfloat16(a.w);
  o.h[4] = __float2bfloat16(b.x); o.h[5] = __float2bfloat16(b.y);
  o.h[6] = __float2bfloat16(b.z); o.h[7] = __float2bfloat16(b.w);
  *(short8*)(xb + (size_t)n * KP0 + k0) = o.v;
}

__global__ __launch_bounds__(256) void convT_w_kernel(const float* __restrict__ W,
    __hip_bfloat16* __restrict__ Wt, int K, int Kp) {
  int idx = blockIdx.x * 256 + threadIdx.x;
  if (idx >= 256 * Kp) return;
  int n = idx / Kp, k = idx - n * Kp;
  Wt[idx] = __float2bfloat16((k < K) ? W[(size_t)k * 256 + n] : 0.f);
}

// ---------------- bf16 MFMA GEMM (m97-style): C[M,256] = A[Mp,Kp] @ Bt[256,Kp]^T ----

__global__ __launch_bounds__(256) void gemm_mfma(const __hip_bfloat16* __restrict__ A,
    const __hip_bfloat16* __restrict__ Bt, __hip_bfloat16* __restrict__ C,
    int M, int Kp) {
  __shared__ __align__(16) __hip_bfloat16 As[128][32];
  __shared__ __align__(16) __hip_bfloat16 Bs[128][32];
  int tid = threadIdx.x;
  int wave = tid >> 6, lane = tid & 63;
  int quad = lane >> 4, mr = lane & 15;
  int row0 = blockIdx.x * 128, col0 = blockIdx.y * 128;
  int wm = (wave & 1) * 64, wn = (wave >> 1) * 64;
  floatx4 acc[4][4] = {};

  int srow = (lane >> 2);
  int kslot = lane & 3;
  int kc = (kslot ^ (srow & 3)) * 8;

  for (int k0 = 0; k0 < Kp; k0 += 32) {
#pragma unroll
    for (int j = 0; j < 2; ++j) {
      int r = wave * 32 + j * 16 + srow;
      gl_lds16(A + (size_t)(row0 + r) * Kp + k0 + kc, &As[wave * 32 + j * 16][0]);
      gl_lds16(Bt + (size_t)(col0 + r) * Kp + k0 + kc, &Bs[wave * 32 + j * 16][0]);
    }
    __syncthreads();
    short8 af[4], bfr[4];
#pragma unroll
    for (int r = 0; r < 4; ++r) {
      int row = wm + r * 16 + mr;
      af[r] = *(const short8*)&As[row][(quad ^ (row & 3)) * 8];
      int col = wn + r * 16 + mr;
      bfr[r] = *(const short8*)&Bs[col][(quad ^ (col & 3)) * 8];
    }
#pragma unroll
    for (int r = 0; r < 4; ++r)
#pragma unroll
      for (int c = 0; c < 4; ++c)
        acc[r][c] = __builtin_amdgcn_mfma_f32_16x16x32_bf16(af[r], bfr[c], acc[r][c], 0, 0, 0);
    __syncthreads();
  }
#pragma unroll
  for (int r = 0; r < 4; ++r) {
#pragma unroll
    for (int c = 0; c < 4; ++c) {
#pragma unroll
      for (int i = 0; i < 4; ++i) {
        int row = row0 + wm + r * 16 + quad * 4 + i;
        int col = wn + c * 16 + mr + col0;
        if (row < M) C[(size_t)row * HID + col] = __float2bfloat16(acc[r][c][i]);
      }
    }
  }
}

// ---------------- per-node attention logits (bf16 H, vectorized) ----------------

__global__ __launch_bounds__(256) void node_logits_kernel(const __hip_bfloat16* __restrict__ H,
    const float* __restrict__ a_src, const float* __restrict__ a_dst,
    float* __restrict__ en_src, float* __restrict__ en_dst, int N) {
  int idx = blockIdx.x * 256 + threadIdx.x;
  if (idx >= N * HEADS) return;
  int n = idx >> 3, h = idx & 7;
  const uint4* Hp = (const uint4*)(H + (size_t)n * HID + h * 32);
  const float* S = a_src + h * 32;
  const float* D = a_dst + h * 32;
  float es = 0.f, ed = 0.f;
#pragma unroll
  for (int j = 0; j < 4; ++j) {
    uint4 u = Hp[j];
    unsigned w[4] = {u.x, u.y, u.z, u.w};
#pragma unroll
    for (int p = 0; p < 4; ++p) {
      float lo = blo(w[p]);
      float hi = bhi(w[p]);
      int c = j * 8 + p * 2;
      es += lo * S[c] + hi * S[c + 1];
      ed += lo * D[c] + hi * D[c + 1];
    }
  }
  en_src[idx] = es;
  en_dst[idx] = ed;
}

// ---------------- fused stats + aggregation: one wave per dst node ----------------
// Agg pass deepened to 8 edges/iter (4 paired uintx4 gathers in flight) for MLP.

__global__ __launch_bounds__(256) void gat_agg_kernel(const __hip_bfloat16* __restrict__ H,
    const float* __restrict__ en_src, const float* __restrict__ en_dst,
    const int* __restrict__ rowptr, const int* __restrict__ csr_src,
    const float* __restrict__ bias, __hip_bfloat16* __restrict__ hb,
    int apply_elu, int N) {
  int wave = threadIdx.x >> 6;
  int lane = threadIdx.x & 63;
  int n = blockIdx.x * 4 + wave;
  if (n >= N) return;
  int h = lane >> 3;
  int slot = lane & 7;
  int beg = rowptr[n], end = rowptr[n + 1];
  float ed = en_dst[n * HEADS + h];

  float m = -1e30f, s = 0.f;
  for (int e = beg + slot; e < end; e += 8) {
    int src = csr_src[e];
    float v = en_src[src * HEADS + h] + ed;
    v = (v > 0.f) ? v : 0.2f * v;
    float mn = fmaxf(m, v);
    s = s * __expf(m - mn) + __expf(v - mn);
    m = mn;
  }
#pragma unroll
  for (int off = 1; off < 8; off <<= 1) {
    float mo = __shfl_xor(m, off);
    float so = __shfl_xor(s, off);
    float mn = fmaxf(m, mo);
    s = s * __expf(m - mn) + so * __expf(mo - mn);
    m = mn;
  }
  float rs = 1.f / (s + 1e-16f);

  // redistribute per-head stats to channel-owner layout
  int eo = lane >> 5;          // 0: even edges, 1: odd edges
  int cl = lane & 31;          // channel group: ch cl*8 .. cl*8+7
  int hh = cl >> 2;            // head of my channels
  float m2 = __shfl(m, hh * 8);
  float rs2 = __shfl(rs, hh * 8);
  float ed2 = __shfl(ed, hh * 8);

  float acc[8] = {0.f, 0.f, 0.f, 0.f, 0.f, 0.f, 0.f, 0.f};
  const __hip_bfloat16* Hc = H + cl * 8;
  for (int cs = beg; cs < end; cs += 64) {
    int cnt = min(64, end - cs);
    int myidx = csr_src[cs + ((lane < cnt) ? lane : (cnt - 1))];
    int i = 0;
    for (; i + 8 <= cnt; i += 8) {
      int s0 = __shfl(myidx, i + eo);
      int s1 = __shfl(myidx, i + 2 + eo);
      int s2 = __shfl(myidx, i + 4 + eo);
      int s3 = __shfl(myidx, i + 6 + eo);
      uintx4 g0 = *(const uintx4*)(Hc + (size_t)s0 * HID);
      uintx4 g1 = *(const uintx4*)(Hc + (size_t)s1 * HID);
      uintx4 g2 = *(const uintx4*)(Hc + (size_t)s2 * HID);
      uintx4 g3 = *(const uintx4*)(Hc + (size_t)s3 * HID);
      float v0 = en_src[s0 * HEADS + hh] + ed2;
      float v1 = en_src[s1 * HEADS + hh] + ed2;
      float v2 = en_src[s2 * HEADS + hh] + ed2;
      float v3 = en_src[s3 * HEADS + hh] + ed2;
      v0 = (v0 > 0.f) ? v0 : 0.2f * v0;
      v1 = (v1 > 0.f) ? v1 : 0.2f * v1;
      v2 = (v2 > 0.f) ? v2 : 0.2f * v2;
      v3 = (v3 > 0.f) ? v3 : 0.2f * v3;
      float w0 = __expf(v0 - m2) * rs2;
      float w1 = __expf(v1 - m2) * rs2;
      float w2 = __expf(v2 - m2) * rs2;
      float w3 = __expf(v3 - m2) * rs2;
      acc8(acc, g0, w0);
      acc8(acc, g1, w1);
      acc8(acc, g2, w2);
      acc8(acc, g3, w3);
    }
    for (; i + 4 <= cnt; i += 4) {
      int sa = __shfl(myidx, i + eo);
      int sb = __shfl(myidx, i + 2 + eo);
      uintx4 ga = *(const uintx4*)(Hc + (size_t)sa * HID);
      uintx4 gb = *(const uintx4*)(Hc + (size_t)sb * HID);
      float va = en_src[sa * HEADS + hh] + ed2;
      float vb = en_src[sb * HEADS + hh] + ed2;
      va = (va > 0.f) ? va : 0.2f * va;
      vb = (vb > 0.f) ? vb : 0.2f * vb;
      float wa = __expf(va - m2) * rs2;
      float wb = __expf(vb - m2) * rs2;
      acc8(acc, ga, wa);
      acc8(acc, gb, wb);
    }
    for (; i < cnt; i += 2) {
      int j = i + eo;
      int jj = (j < cnt) ? j : (cnt - 1);
      int sa = __shfl(myidx, jj);
      uintx4 ga = *(const uintx4*)(Hc + (size_t)sa * HID);
      float va = en_src[sa * HEADS + hh] + ed2;
      va = (va > 0.f) ? va : 0.2f * va;
      float wa = (j < cnt) ? __expf(va - m2) * rs2 : 0.f;
      acc8(acc, ga, wa);
    }
  }
#pragma unroll
  for (int i = 0; i < 8; ++i) acc[i] += __shfl_xor(acc[i], 32);

  if (eo == 0) {
    const float4* bp = (const float4*)(bias + cl * 8);
    float4 b0 = bp[0], b1 = bp[1];
    float o[8];
    o[0] = acc[0] + b0.x; o[1] = acc[1] + b0.y;
    o[2] = acc[2] + b0.z; o[3] = acc[3] + b0.w;
    o[4] = acc[4] + b1.x; o[5] = acc[5] + b1.y;
    o[6] = acc[6] + b1.z; o[7] = acc[7] + b1.w;
    if (apply_elu) {
#pragma unroll
      for (int i = 0; i < 8; ++i) o[i] = (o[i] > 0.f) ? o[i] : expm1f(o[i]);
    }
    union { __hip_bfloat16 hh8[8]; uintx4 u; } pk;
#pragma unroll
    for (int i = 0; i < 8; ++i) pk.hh8[i] = __float2bfloat16(o[i]);
    __builtin_nontemporal_store(pk.u, (uintx4*)(hb + (size_t)n * HID + cl * 8));
  }
}

// ---------------- JK max + final linear + log_softmax (bf16 h inputs) ----------------
// grid-stride x FKG: Wf staged to LDS once per block, reused for 4*FKG nodes.

__global__ __launch_bounds__(256) void final_kernel(const __hip_bfloat16* __restrict__ hb0,
    const __hip_bfloat16* __restrict__ hb1, const __hip_bfloat16* __restrict__ hb2,
    const float* __restrict__ Wf, const float* __restrict__ bf,
    float* __restrict__ out, int N) {
  __shared__ float Wfs[HID * 40];
  __shared__ float jks[4][HID];
  int tid = threadIdx.x;
  for (int i = tid; i < HID * 40; i += 256) Wfs[i] = Wf[i];
  int sub = tid >> 6, lane = tid & 63;
  int nbase = blockIdx.x * 4 * FKG;
  __syncthreads();
  for (int g = 0; g < FKG; ++g) {
    int n = nbase + g * 4 + sub;
    if (n < N) {
      uint2 a = *(const uint2*)(hb0 + (size_t)n * HID + lane * 4);
      uint2 b = *(const uint2*)(hb1 + (size_t)n * HID + lane * 4);
      uint2 c = *(const uint2*)(hb2 + (size_t)n * HID + lane * 4);
      float4 r;
      r.x = fmaxf(fmaxf(blo(a.x), blo(b.x)), blo(c.x));
      r.y = fmaxf(fmaxf(bhi(a.x), bhi(b.x)), bhi(c.x));
      r.z = fmaxf(fmaxf(blo(a.y), blo(b.y)), blo(c.y));
      r.w = fmaxf(fmaxf(bhi(a.y), bhi(b.y)), bhi(c.y));
      *(float4*)&jks[sub][lane * 4] = r;
    }
    __syncthreads();
    float logit = -INFINITY;
    if (lane < 40 && n < N) {
      float accv = bf[lane];
#pragma unroll 8
      for (int k = 0; k < HID; ++k) accv += jks[sub][k] * Wfs[k * 40 + lane];
      logit = accv;
    }
    float mx = logit;
#pragma unroll
    for (int off = 32; off > 0; off >>= 1) mx = fmaxf(mx, __shfl_down(mx, off));
    mx = __shfl(mx, 0);
    float ex = (lane < 40 && n < N) ? __expf(logit - mx) : 0.f;
    float sm = ex;
#pragma unroll
    for (int off = 32; off > 0; off >>= 1) sm += __shfl_down(sm, off);
    sm = __shfl(sm, 0);
    if (lane < 40 && n < N) out[(size_t)n * 40 + lane] = logit - mx - __logf(sm);
    __syncthreads();
  }
}

// ---------------- launch ----------------

extern "C" void kernel_launch(void* const* d_in, const int* in_sizes, int n_in,
                              void* d_out, int out_size, void* d_ws, size_t ws_size,
                              hipStream_t stream) {
  (void)n_in; (void)out_size; (void)ws_size;
  const float* x   = (const float*)d_in[0];
  const int*   ei  = (const int*)d_in[1];
  const float* W0  = (const float*)d_in[2];
  const float* as0 = (const float*)d_in[3];
  const float* ad0 = (const float*)d_in[4];
  const float* b0  = (const float*)d_in[5];
  const float* W1  = (const float*)d_in[6];
  const float* as1 = (const float*)d_in[7];
  const float* ad1 = (const float*)d_in[8];
  const float* b1  = (const float*)d_in[9];
  const float* W2  = (const float*)d_in[10];
  const float* as2 = (const float*)d_in[11];
  const float* ad2 = (const float*)d_in[12];
  const float* b2  = (const float*)d_in[13];
  const float* Wf  = (const float*)d_in[14];
  const float* bf  = (const float*)d_in[15];
  float* out = (float*)d_out;

  const int E = in_sizes[1] / 2;
  const int IN_CH = in_sizes[2] / HID;      // 500
  const int N = in_sizes[0] / IN_CH;        // 100000
  const int Etot = E + N;
  const int Mp = ((N + 127) / 128) * 128;   // 100096
  const int NB = (N + 127) >> 7;            // 782 buckets of 128 dst nodes
  const int NBLK = (Etot + EPB - 1) / EPB;  // ~202 partition blocks
  const int L = NB * NBLK;
  const int NBS = (L + 1023) / 1024;        // 155 scan blocks (must be <= 256)
  const size_t NM = (size_t)N * HID;
  const size_t MpM = (size_t)Mp * HID;

  __hip_bfloat16* xb  = (__hip_bfloat16*)d_ws;            // Mp*KP0
  __hip_bfloat16* Htb = xb + (size_t)Mp * KP0;            // N*HID
  __hip_bfloat16* hb0 = Htb + NM;                         // Mp*HID (bf16 h0)
  __hip_bfloat16* hb1 = hb0 + MpM;                        // Mp*HID (bf16 h1)
  __hip_bfloat16* hb2 = hb1 + MpM;                        // Mp*HID (bf16 h2)
  __hip_bfloat16* Wt0 = hb2 + MpM;                        // 256*KP0
  __hip_bfloat16* Wt1 = Wt0 + 256 * KP0;                  // 256*256
  __hip_bfloat16* Wt2 = Wt1 + 256 * 256;
  float* fbase = (float*)(Wt2 + 256 * 256);
  float* en_s = fbase;
  float* en_d = en_s + (size_t)N * HEADS;
  // int arrays, each start rounded up to 16B
  int* rowptr  = (int*)(en_d + (size_t)N * HEADS);        // N+1
  int* csr_src = rowptr + (((size_t)N + 1 + 3) & ~(size_t)3);   // Etot
  int* F       = csr_src + (((size_t)Etot + 3) & ~(size_t)3);   // L
  int* S       = F + (((size_t)L + 3) & ~(size_t)3);            // L+1
  int* bsum    = S + (((size_t)L + 1 + 3) & ~(size_t)3);        // NBS
  int* bb      = bsum + 256;                                    // NBS
  unsigned* stag = (unsigned*)(bb + 256);                       // Etot

  edge_hist_kernel<<<NBLK, 256, 0, stream>>>(ei, F, E, Etot, NB, NBLK);
  scan_part_kernel<<<NBS, 256, 0, stream>>>(F, bsum, L);
  scan_bsum_kernel<<<1, 256, 0, stream>>>(bsum, bb, S, NBS, L);
  scan_apply_kernel<<<NBS, 256, 0, stream>>>(F, bb, S, L);
  edge_scatter_kernel<<<NBLK, 256, 0, stream>>>(ei, S, stag, E, Etot, NB, NBLK);
  bucket_build_kernel<<<NB, 256, 0, stream>>>(stag, S, NBLK, rowptr, csr_src, N);

  conv_x_kernel<<<((size_t)N * (KP0 / 8) + 255) / 256, 256, 0, stream>>>(x, xb, N, IN_CH);
  convT_w_kernel<<<(256 * KP0 + 255) / 256, 256, 0, stream>>>(W0, Wt0, IN_CH, KP0);
  convT_w_kernel<<<(256 * 256 + 255) / 256, 256, 0, stream>>>(W1, Wt1, HID, HID);
  convT_w_kernel<<<(256 * 256 + 255) / 256, 256, 0, stream>>>(W2, Wt2, HID, HID);

  dim3 ggrid(Mp / 128, 2);
  int lblocks = (N * HEADS + 255) / 256;
  int ablocks = (N + 3) / 4;
  int fblocks = (N + 4 * FKG - 1) / (4 * FKG);

  // layer 0
  gemm_mfma<<<ggrid, 256, 0, stream>>>(xb, Wt0, Htb, N, KP0);
  node_logits_kernel<<<lblocks, 256, 0, stream>>>(Htb, as0, ad0, en_s, en_d, N);
  gat_agg_kernel<<<ablocks, 256, 0, stream>>>(Htb, en_s, en_d, rowptr, csr_src, b0, hb0, 1, N);
  // layer 1
  gemm_mfma<<<ggrid, 256, 0, stream>>>(hb0, Wt1, Htb, N, HID);
  node_logits_kernel<<<lblocks, 256, 0, stream>>>(Htb, as1, ad1, en_s, en_d, N);
  gat_agg_kernel<<<ablocks, 256, 0, stream>>>(Htb, en_s, en_d, rowptr, csr_src, b1, hb1, 1, N);
  // layer 2
  gemm_mfma<<<ggrid, 256, 0, stream>>>(hb1, Wt2, Htb, N, HID);
  node_logits_kernel<<<lblocks, 256, 0, stream>>>(Htb, as2, ad2, en_s, en_d, N);
  gat_agg_kernel<<<ablocks, 256, 0, stream>>>(Htb, en_s, en_d, rowptr, csr_src, b2, hb2, 0, N);

  final_kernel<<<fblocks, 256, 0, stream>>>(hb0, hb1, hb2, Wf, bf, out, N);
}

// Round 9
// 1692.070 us; speedup vs baseline: 1.0219x; 1.0219x over previous
//
#include <hip/hip_runtime.h>
#include <hip/hip_bf16.h>
#include <math.h>

#define HID 256
#define HEADS 8
#define KP0 512
#define EPB 16384      // edges per block in hist/scatter passes
#define NBMAX 1024     // max buckets (N/128 = 782 here)
#define FKG 16         // node-groups per final_kernel block

typedef __attribute__((ext_vector_type(8))) short short8;
typedef __attribute__((ext_vector_type(4))) float floatx4;
typedef __attribute__((ext_vector_type(4))) unsigned uintx4;

__device__ __forceinline__ void gl_lds16(const void* g, void* l) {
  __builtin_amdgcn_global_load_lds(
      (const __attribute__((address_space(1))) void*)g,
      (__attribute__((address_space(3))) void*)l, 16, 0, 0);
}

__device__ __forceinline__ float blo(unsigned u) { return __uint_as_float(u << 16); }
__device__ __forceinline__ float bhi(unsigned u) { return __uint_as_float(u & 0xffff0000u); }

__device__ __forceinline__ void acc8(float* acc, uintx4 g, float w) {
  acc[0] += w * blo(g[0]); acc[1] += w * bhi(g[0]);
  acc[2] += w * blo(g[1]); acc[3] += w * bhi(g[1]);
  acc[4] += w * blo(g[2]); acc[5] += w * bhi(g[2]);
  acc[6] += w * blo(g[3]); acc[7] += w * bhi(g[3]);
}

// ---------------- contention-free bucketed CSR build ----------------

__global__ __launch_bounds__(256) void edge_hist_kernel(const int* __restrict__ ei,
    int* __restrict__ F, int E, int Etot, int NB, int NBLK) {
  __shared__ int hist[NBMAX];
  int blk = blockIdx.x, t = threadIdx.x;
  for (int i = t; i < NBMAX; i += 256) hist[i] = 0;
  __syncthreads();
  int base = blk * EPB;
  int lim = min(EPB, Etot - base);
  for (int i = t; i < lim; i += 256) {
    int idx = base + i;
    int d = (idx < E) ? ei[E + idx] : (idx - E);
    atomicAdd(&hist[d >> 7], 1);
  }
  __syncthreads();
  for (int b = t; b < NB; b += 256) F[b * NBLK + blk] = hist[b];
}

__global__ __launch_bounds__(256) void scan_part_kernel(const int* __restrict__ F,
    int* __restrict__ bsum, int L) {
  __shared__ int ws[4];
  int blk = blockIdx.x, t = threadIdx.x;
  int base = blk * 1024 + t * 4;
  int s = 0;
  if (base + 3 < L) {
    int4 v = *(const int4*)(F + base);
    s = v.x + v.y + v.z + v.w;
  } else {
    for (int i = 0; i < 4; ++i) if (base + i < L) s += F[base + i];
  }
#pragma unroll
  for (int off = 1; off < 64; off <<= 1) s += __shfl_xor(s, off);
  if ((t & 63) == 0) ws[t >> 6] = s;
  __syncthreads();
  if (t == 0) bsum[blk] = ws[0] + ws[1] + ws[2] + ws[3];
}

__global__ __launch_bounds__(256) void scan_bsum_kernel(const int* __restrict__ bsum,
    int* __restrict__ bb, int* __restrict__ S, int NBS, int L) {
  __shared__ int ps[256];
  int t = threadIdx.x;
  int v = (t < NBS) ? bsum[t] : 0;
  ps[t] = v;
  __syncthreads();
  for (int off = 1; off < 256; off <<= 1) {
    int add = (t >= off) ? ps[t - off] : 0;
    __syncthreads();
    ps[t] += add;
    __syncthreads();
  }
  if (t < NBS) bb[t] = (t == 0) ? 0 : ps[t - 1];
  if (t == 255) S[L] = ps[255];
}

__global__ __launch_bounds__(256) void scan_apply_kernel(const int* __restrict__ F,
    const int* __restrict__ bb, int* __restrict__ S, int L) {
  __shared__ int ps[256];
  int blk = blockIdx.x, t = threadIdx.x;
  int base = blk * 1024 + t * 4;
  int v0 = 0, v1 = 0, v2 = 0, v3 = 0;
  if (base + 3 < L) {
    int4 w = *(const int4*)(F + base);
    v0 = w.x; v1 = w.y; v2 = w.z; v3 = w.w;
  } else {
    if (base + 0 < L) v0 = F[base + 0];
    if (base + 1 < L) v1 = F[base + 1];
    if (base + 2 < L) v2 = F[base + 2];
    if (base + 3 < L) v3 = F[base + 3];
  }
  ps[t] = v0 + v1 + v2 + v3;
  __syncthreads();
  for (int off = 1; off < 256; off <<= 1) {
    int add = (t >= off) ? ps[t - off] : 0;
    __syncthreads();
    ps[t] += add;
    __syncthreads();
  }
  int run = bb[blk] + ((t == 0) ? 0 : ps[t - 1]);
  if (base + 0 < L) S[base + 0] = run; run += v0;
  if (base + 1 < L) S[base + 1] = run; run += v1;
  if (base + 2 < L) S[base + 2] = run; run += v2;
  if (base + 3 < L) S[base + 3] = run;
}

__global__ __launch_bounds__(256) void edge_scatter_kernel(const int* __restrict__ ei,
    const int* __restrict__ S, unsigned* __restrict__ stag, int E, int Etot,
    int NB, int NBLK) {
  __shared__ int cur[NBMAX];
  int blk = blockIdx.x, t = threadIdx.x;
  for (int b = t; b < NB; b += 256) cur[b] = S[b * NBLK + blk];
  __syncthreads();
  int base = blk * EPB;
  int lim = min(EPB, Etot - base);
  for (int i = t; i < lim; i += 256) {
    int idx = base + i;
    int s, d;
    if (idx < E) { s = ei[idx]; d = ei[E + idx]; }
    else { s = idx - E; d = s; }
    int pos = atomicAdd(&cur[d >> 7], 1);
    stag[pos] = ((unsigned)(d & 127) << 17) | (unsigned)s;
  }
}

__global__ __launch_bounds__(256) void bucket_build_kernel(const unsigned* __restrict__ stag,
    const int* __restrict__ S, int NBLK,
    int* __restrict__ rowptr, int* __restrict__ csr_src, int N) {
  __shared__ int deg[128], pfx[128], cur[128];
  int b = blockIdx.x;
  int t = threadIdx.x;
  int gbase = S[(size_t)b * NBLK];
  int gend = S[(size_t)(b + 1) * NBLK];
  int cnt = gend - gbase;
  int node0 = b << 7;
  int nn = min(128, N - node0);
  if (t < 128) deg[t] = 0;
  __syncthreads();
  const unsigned* sb = stag + gbase;
  for (int i = t; i < cnt; i += 256) atomicAdd(&deg[sb[i] >> 17], 1);
  __syncthreads();
  if (t == 0) {
    int run = 0;
#pragma unroll 8
    for (int i = 0; i < 128; ++i) { pfx[i] = run; run += deg[i]; }
  }
  __syncthreads();
  if (t < 128) cur[t] = pfx[t];
  if (t < nn) rowptr[node0 + t] = gbase + pfx[t];
  if (b == (int)gridDim.x - 1 && t == 0) rowptr[N] = gbase + cnt;
  __syncthreads();
  for (int i = t; i < cnt; i += 256) {
    unsigned v = sb[i];
    int dl = v >> 17;
    int pos = gbase + atomicAdd(&cur[dl], 1);
    csr_src[pos] = (int)(v & 0x1ffff);
  }
}

// ---------------- weight transpose (tiny) ----------------

__global__ __launch_bounds__(256) void convT_w_kernel(const float* __restrict__ W,
    __hip_bfloat16* __restrict__ Wt, int K, int Kp) {
  int idx = blockIdx.x * 256 + threadIdx.x;
  if (idx >= 256 * Kp) return;
  int n = idx / Kp, k = idx - n * Kp;
  Wt[idx] = __float2bfloat16((k < K) ? W[(size_t)k * 256 + n] : 0.f);
}

// ---------------- GEMM epilogue: C write + fused per-node logits ----------------
// Block covers all 256 cols; wave's 64-col span = heads (wn>>5), (wn>>5)+1.
// es[row,h] = sum_col C[row][col]*a_src[col] via 16-lane shfl reduce over mr.

__device__ __forceinline__ void gemm_epilogue(floatx4 (&acc)[4][4],
    __hip_bfloat16* __restrict__ C, float* __restrict__ en_s, float* __restrict__ en_d,
    const float* __restrict__ a_src, const float* __restrict__ a_dst,
    int row0, int wm, int wn, int quad, int mr, int M) {
#pragma unroll
  for (int r = 0; r < 4; ++r) {
#pragma unroll
    for (int c = 0; c < 4; ++c) {
#pragma unroll
      for (int i = 0; i < 4; ++i) {
        int row = row0 + wm + r * 16 + quad * 4 + i;
        int col = wn + c * 16 + mr;
        if (row < M) C[(size_t)row * HID + col] = __float2bfloat16(acc[r][c][i]);
      }
    }
  }
  float as_c[4], ad_c[4];
#pragma unroll
  for (int c = 0; c < 4; ++c) {
    int col = wn + c * 16 + mr;
    as_c[c] = a_src[col];
    ad_c[c] = a_dst[col];
  }
  int h0 = wn >> 5;
#pragma unroll
  for (int r = 0; r < 4; ++r) {
#pragma unroll
    for (int i = 0; i < 4; ++i) {
      float e0 = acc[r][0][i] * as_c[0] + acc[r][1][i] * as_c[1];
      float e1 = acc[r][2][i] * as_c[2] + acc[r][3][i] * as_c[3];
      float d0 = acc[r][0][i] * ad_c[0] + acc[r][1][i] * ad_c[1];
      float d1 = acc[r][2][i] * ad_c[2] + acc[r][3][i] * ad_c[3];
#pragma unroll
      for (int off = 1; off < 16; off <<= 1) {
        e0 += __shfl_xor(e0, off);
        e1 += __shfl_xor(e1, off);
        d0 += __shfl_xor(d0, off);
        d1 += __shfl_xor(d1, off);
      }
      if (mr == 0) {
        int row = row0 + wm + r * 16 + quad * 4 + i;
        if (row < M) {
          en_s[row * HEADS + h0] = e0;
          en_s[row * HEADS + h0 + 1] = e1;
          en_d[row * HEADS + h0] = d0;
          en_d[row * HEADS + h0 + 1] = d1;
        }
      }
    }
  }
}

// ---------------- bf16 GEMM, BM=128 BN=256 BK=32, 512 thr / 8 waves ----------------
// C[M,256] = A[Mp,Kp] @ Bt[256,Kp]^T, A read ONCE, + fused logits epilogue.

__global__ __launch_bounds__(512) void gemm_bf16(const __hip_bfloat16* __restrict__ A,
    const __hip_bfloat16* __restrict__ Bt, __hip_bfloat16* __restrict__ C,
    float* __restrict__ en_s, float* __restrict__ en_d,
    const float* __restrict__ a_src, const float* __restrict__ a_dst,
    int M, int Kp) {
  __shared__ __align__(16) __hip_bfloat16 As[128][32];
  __shared__ __align__(16) __hip_bfloat16 Bs[256][32];
  int tid = threadIdx.x;
  int wave = tid >> 6, lane = tid & 63;
  int quad = lane >> 4, mr = lane & 15;
  int row0 = blockIdx.x * 128;
  int wm = (wave & 1) * 64, wn = (wave >> 1) * 64;
  floatx4 acc[4][4] = {};
  int srow = lane >> 2;
  int kslot = lane & 3;
  int kc = (kslot ^ (srow & 3)) * 8;

  for (int k0 = 0; k0 < Kp; k0 += 32) {
    gl_lds16(A + (size_t)(row0 + wave * 16 + srow) * Kp + k0 + kc, &As[wave * 16][0]);
#pragma unroll
    for (int j = 0; j < 2; ++j)
      gl_lds16(Bt + (size_t)(wave * 32 + j * 16 + srow) * Kp + k0 + kc, &Bs[wave * 32 + j * 16][0]);
    __syncthreads();
    short8 af[4], bfr[4];
#pragma unroll
    for (int r = 0; r < 4; ++r) {
      int row = wm + r * 16 + mr;
      af[r] = *(const short8*)&As[row][(quad ^ (row & 3)) * 8];
      int col = wn + r * 16 + mr;
      bfr[r] = *(const short8*)&Bs[col][(quad ^ (col & 3)) * 8];
    }
#pragma unroll
    for (int r = 0; r < 4; ++r)
#pragma unroll
      for (int c = 0; c < 4; ++c)
        acc[r][c] = __builtin_amdgcn_mfma_f32_16x16x32_bf16(af[r], bfr[c], acc[r][c], 0, 0, 0);
    __syncthreads();
  }
  gemm_epilogue(acc, C, en_s, en_d, a_src, a_dst, row0, wm, wn, quad, mr, M);
}

// ---------------- layer-0 GEMM: fp32 A read directly (conv fused) ----------------
// A = x[M][K] fp32 (K=500); reg-stage + convert + ds_write into the same
// XOR-swizzled LDS layout. B = Wt0[256][Kp] bf16 (zero k-padded).

__global__ __launch_bounds__(512) void gemm_f32a(const float* __restrict__ X,
    const __hip_bfloat16* __restrict__ Bt, __hip_bfloat16* __restrict__ C,
    float* __restrict__ en_s, float* __restrict__ en_d,
    const float* __restrict__ a_src, const float* __restrict__ a_dst,
    int M, int K, int Kp) {
  __shared__ __align__(16) __hip_bfloat16 As[128][32];
  __shared__ __align__(16) __hip_bfloat16 Bs[256][32];
  int tid = threadIdx.x;
  int wave = tid >> 6, lane = tid & 63;
  int quad = lane >> 4, mr = lane & 15;
  int row0 = blockIdx.x * 128;
  int wm = (wave & 1) * 64, wn = (wave >> 1) * 64;
  floatx4 acc[4][4] = {};
  int srow = lane >> 2;
  int kslot = lane & 3;
  int kc = (kslot ^ (srow & 3)) * 8;

  for (int k0 = 0; k0 < Kp; k0 += 32) {
    // A: row = row0 + wave*16 + srow, global k chunk kg..kg+7 (kg = k0+kc)
    {
      int row = row0 + wave * 16 + srow;
      int kg = k0 + kc;
      float v[8];
      if (row < M && kg + 7 < K) {
        const float* xp = X + (size_t)row * K + kg;
        float4 a = *(const float4*)xp;
        float4 b = *(const float4*)(xp + 4);
        v[0] = a.x; v[1] = a.y; v[2] = a.z; v[3] = a.w;
        v[4] = b.x; v[5] = b.y; v[6] = b.z; v[7] = b.w;
      } else {
#pragma unroll
        for (int j = 0; j < 8; ++j)
          v[j] = (row < M && kg + j < K) ? X[(size_t)row * K + kg + j] : 0.f;
      }
      union { short8 s; __hip_bfloat16 h[8]; } pk;
#pragma unroll
      for (int j = 0; j < 8; ++j) pk.h[j] = __float2bfloat16(v[j]);
      *(short8*)&As[wave * 16 + srow][kslot * 8] = pk.s;
    }
#pragma unroll
    for (int j = 0; j < 2; ++j)
      gl_lds16(Bt + (size_t)(wave * 32 + j * 16 + srow) * Kp + k0 + kc, &Bs[wave * 32 + j * 16][0]);
    __syncthreads();
    short8 af[4], bfr[4];
#pragma unroll
    for (int r = 0; r < 4; ++r) {
      int row = wm + r * 16 + mr;
      af[r] = *(const short8*)&As[row][(quad ^ (row & 3)) * 8];
      int col = wn + r * 16 + mr;
      bfr[r] = *(const short8*)&Bs[col][(quad ^ (col & 3)) * 8];
    }
#pragma unroll
    for (int r = 0; r < 4; ++r)
#pragma unroll
      for (int c = 0; c < 4; ++c)
        acc[r][c] = __builtin_amdgcn_mfma_f32_16x16x32_bf16(af[r], bfr[c], acc[r][c], 0, 0, 0);
    __syncthreads();
  }
  gemm_epilogue(acc, C, en_s, en_d, a_src, a_dst, row0, wm, wn, quad, mr, M);
}

// ---------------- fused stats + aggregation: one wave per dst node ----------------

__global__ __launch_bounds__(256) void gat_agg_kernel(const __hip_bfloat16* __restrict__ H,
    const float* __restrict__ en_src, const float* __restrict__ en_dst,
    const int* __restrict__ rowptr, const int* __restrict__ csr_src,
    const float* __restrict__ bias, __hip_bfloat16* __restrict__ hb,
    int apply_elu, int N) {
  int wave = threadIdx.x >> 6;
  int lane = threadIdx.x & 63;
  int n = blockIdx.x * 4 + wave;
  if (n >= N) return;
  int h = lane >> 3;
  int slot = lane & 7;
  int beg = rowptr[n], end = rowptr[n + 1];
  float ed = en_dst[n * HEADS + h];

  float m = -1e30f, s = 0.f;
  for (int e = beg + slot; e < end; e += 8) {
    int src = csr_src[e];
    float v = en_src[src * HEADS + h] + ed;
    v = (v > 0.f) ? v : 0.2f * v;
    float mn = fmaxf(m, v);
    s = s * __expf(m - mn) + __expf(v - mn);
    m = mn;
  }
#pragma unroll
  for (int off = 1; off < 8; off <<= 1) {
    float mo = __shfl_xor(m, off);
    float so = __shfl_xor(s, off);
    float mn = fmaxf(m, mo);
    s = s * __expf(m - mn) + so * __expf(mo - mn);
    m = mn;
  }
  float rs = 1.f / (s + 1e-16f);

  int eo = lane >> 5;
  int cl = lane & 31;
  int hh = cl >> 2;
  float m2 = __shfl(m, hh * 8);
  float rs2 = __shfl(rs, hh * 8);
  float ed2 = __shfl(ed, hh * 8);

  float acc[8] = {0.f, 0.f, 0.f, 0.f, 0.f, 0.f, 0.f, 0.f};
  const __hip_bfloat16* Hc = H + cl * 8;
  for (int cs = beg; cs < end; cs += 64) {
    int cnt = min(64, end - cs);
    int myidx = csr_src[cs + ((lane < cnt) ? lane : (cnt - 1))];
    int i = 0;
    for (; i + 8 <= cnt; i += 8) {
      int s0 = __shfl(myidx, i + eo);
      int s1 = __shfl(myidx, i + 2 + eo);
      int s2 = __shfl(myidx, i + 4 + eo);
      int s3 = __shfl(myidx, i + 6 + eo);
      uintx4 g0 = *(const uintx4*)(Hc + (size_t)s0 * HID);
      uintx4 g1 = *(const uintx4*)(Hc + (size_t)s1 * HID);
      uintx4 g2 = *(const uintx4*)(Hc + (size_t)s2 * HID);
      uintx4 g3 = *(const uintx4*)(Hc + (size_t)s3 * HID);
      float v0 = en_src[s0 * HEADS + hh] + ed2;
      float v1 = en_src[s1 * HEADS + hh] + ed2;
      float v2 = en_src[s2 * HEADS + hh] + ed2;
      float v3 = en_src[s3 * HEADS + hh] + ed2;
      v0 = (v0 > 0.f) ? v0 : 0.2f * v0;
      v1 = (v1 > 0.f) ? v1 : 0.2f * v1;
      v2 = (v2 > 0.f) ? v2 : 0.2f * v2;
      v3 = (v3 > 0.f) ? v3 : 0.2f * v3;
      float w0 = __expf(v0 - m2) * rs2;
      float w1 = __expf(v1 - m2) * rs2;
      float w2 = __expf(v2 - m2) * rs2;
      float w3 = __expf(v3 - m2) * rs2;
      acc8(acc, g0, w0);
      acc8(acc, g1, w1);
      acc8(acc, g2, w2);
      acc8(acc, g3, w3);
    }
    for (; i + 4 <= cnt; i += 4) {
      int sa = __shfl(myidx, i + eo);
      int sb = __shfl(myidx, i + 2 + eo);
      uintx4 ga = *(const uintx4*)(Hc + (size_t)sa * HID);
      uintx4 gb = *(const uintx4*)(Hc + (size_t)sb * HID);
      float va = en_src[sa * HEADS + hh] + ed2;
      float vb = en_src[sb * HEADS + hh] + ed2;
      va = (va > 0.f) ? va : 0.2f * va;
      vb = (vb > 0.f) ? vb : 0.2f * vb;
      float wa = __expf(va - m2) * rs2;
      float wb = __expf(vb - m2) * rs2;
      acc8(acc, ga, wa);
      acc8(acc, gb, wb);
    }
    for (; i < cnt; i += 2) {
      int j = i + eo;
      int jj = (j < cnt) ? j : (cnt - 1);
      int sa = __shfl(myidx, jj);
      uintx4 ga = *(const uintx4*)(Hc + (size_t)sa * HID);
      float va = en_src[sa * HEADS + hh] + ed2;
      va = (va > 0.f) ? va : 0.2f * va;
      float wa = (j < cnt) ? __expf(va - m2) * rs2 : 0.f;
      acc8(acc, ga, wa);
    }
  }
#pragma unroll
  for (int i = 0; i < 8; ++i) acc[i] += __shfl_xor(acc[i], 32);

  if (eo == 0) {
    const float4* bp = (const float4*)(bias + cl * 8);
    float4 b0 = bp[0], b1 = bp[1];
    float o[8];
    o[0] = acc[0] + b0.x; o[1] = acc[1] + b0.y;
    o[2] = acc[2] + b0.z; o[3] = acc[3] + b0.w;
    o[4] = acc[4] + b1.x; o[5] = acc[5] + b1.y;
    o[6] = acc[6] + b1.z; o[7] = acc[7] + b1.w;
    if (apply_elu) {
#pragma unroll
      for (int i = 0; i < 8; ++i) o[i] = (o[i] > 0.f) ? o[i] : expm1f(o[i]);
    }
    union { __hip_bfloat16 hh8[8]; uintx4 u; } pk;
#pragma unroll
    for (int i = 0; i < 8; ++i) pk.hh8[i] = __float2bfloat16(o[i]);
    __builtin_nontemporal_store(pk.u, (uintx4*)(hb + (size_t)n * HID + cl * 8));
  }
}

// ---------------- JK max + final linear + log_softmax (bf16 h inputs) ----------------

__global__ __launch_bounds__(256) void final_kernel(const __hip_bfloat16* __restrict__ hb0,
    const __hip_bfloat16* __restrict__ hb1, const __hip_bfloat16* __restrict__ hb2,
    const float* __restrict__ Wf, const float* __restrict__ bf,
    float* __restrict__ out, int N) {
  __shared__ float Wfs[HID * 40];
  __shared__ float jks[4][HID];
  int tid = threadIdx.x;
  for (int i = tid; i < HID * 40; i += 256) Wfs[i] = Wf[i];
  int sub = tid >> 6, lane = tid & 63;
  int nbase = blockIdx.x * 4 * FKG;
  __syncthreads();
  for (int g = 0; g < FKG; ++g) {
    int n = nbase + g * 4 + sub;
    if (n < N) {
      uint2 a = *(const uint2*)(hb0 + (size_t)n * HID + lane * 4);
      uint2 b = *(const uint2*)(hb1 + (size_t)n * HID + lane * 4);
      uint2 c = *(const uint2*)(hb2 + (size_t)n * HID + lane * 4);
      float4 r;
      r.x = fmaxf(fmaxf(blo(a.x), blo(b.x)), blo(c.x));
      r.y = fmaxf(fmaxf(bhi(a.x), bhi(b.x)), bhi(c.x));
      r.z = fmaxf(fmaxf(blo(a.y), blo(b.y)), blo(c.y));
      r.w = fmaxf(fmaxf(bhi(a.y), bhi(b.y)), bhi(c.y));
      *(float4*)&jks[sub][lane * 4] = r;
    }
    __syncthreads();
    float logit = -INFINITY;
    if (lane < 40 && n < N) {
      float accv = bf[lane];
#pragma unroll 8
      for (int k = 0; k < HID; ++k) accv += jks[sub][k] * Wfs[k * 40 + lane];
      logit = accv;
    }
    float mx = logit;
#pragma unroll
    for (int off = 32; off > 0; off >>= 1) mx = fmaxf(mx, __shfl_down(mx, off));
    mx = __shfl(mx, 0);
    float ex = (lane < 40 && n < N) ? __expf(logit - mx) : 0.f;
    float sm = ex;
#pragma unroll
    for (int off = 32; off > 0; off >>= 1) sm += __shfl_down(sm, off);
    sm = __shfl(sm, 0);
    if (lane < 40 && n < N) out[(size_t)n * 40 + lane] = logit - mx - __logf(sm);
    __syncthreads();
  }
}

// ---------------- launch ----------------

extern "C" void kernel_launch(void* const* d_in, const int* in_sizes, int n_in,
                              void* d_out, int out_size, void* d_ws, size_t ws_size,
                              hipStream_t stream) {
  (void)n_in; (void)out_size; (void)ws_size;
  const float* x   = (const float*)d_in[0];
  const int*   ei  = (const int*)d_in[1];
  const float* W0  = (const float*)d_in[2];
  const float* as0 = (const float*)d_in[3];
  const float* ad0 = (const float*)d_in[4];
  const float* b0  = (const float*)d_in[5];
  const float* W1  = (const float*)d_in[6];
  const float* as1 = (const float*)d_in[7];
  const float* ad1 = (const float*)d_in[8];
  const float* b1  = (const float*)d_in[9];
  const float* W2  = (const float*)d_in[10];
  const float* as2 = (const float*)d_in[11];
  const float* ad2 = (const float*)d_in[12];
  const float* b2  = (const float*)d_in[13];
  const float* Wf  = (const float*)d_in[14];
  const float* bf  = (const float*)d_in[15];
  float* out = (float*)d_out;

  const int E = in_sizes[1] / 2;
  const int IN_CH = in_sizes[2] / HID;      // 500
  const int N = in_sizes[0] / IN_CH;        // 100000
  const int Etot = E + N;
  const int Mp = ((N + 127) / 128) * 128;   // 100096
  const int NB = (N + 127) >> 7;            // 782 buckets
  const int NBLK = (Etot + EPB - 1) / EPB;  // ~202 partition blocks
  const int L = NB * NBLK;
  const int NBS = (L + 1023) / 1024;        // scan blocks (<=256)
  const size_t NM = (size_t)N * HID;
  const size_t MpM = (size_t)Mp * HID;

  __hip_bfloat16* Htb = (__hip_bfloat16*)d_ws;            // N*HID
  __hip_bfloat16* hb0 = Htb + NM;                         // Mp*HID
  __hip_bfloat16* hb1 = hb0 + MpM;                        // Mp*HID
  __hip_bfloat16* hb2 = hb1 + MpM;                        // Mp*HID
  __hip_bfloat16* Wt0 = hb2 + MpM;                        // 256*KP0
  __hip_bfloat16* Wt1 = Wt0 + 256 * KP0;                  // 256*256
  __hip_bfloat16* Wt2 = Wt1 + 256 * 256;
  float* fbase = (float*)(Wt2 + 256 * 256);
  float* en_s = fbase;
  float* en_d = en_s + (size_t)N * HEADS;
  int* rowptr  = (int*)(en_d + (size_t)N * HEADS);        // N+1
  int* csr_src = rowptr + (((size_t)N + 1 + 3) & ~(size_t)3);   // Etot
  int* F       = csr_src + (((size_t)Etot + 3) & ~(size_t)3);   // L
  int* S       = F + (((size_t)L + 3) & ~(size_t)3);            // L+1
  int* bsum    = S + (((size_t)L + 1 + 3) & ~(size_t)3);        // NBS
  int* bb      = bsum + 256;                                    // NBS
  unsigned* stag = (unsigned*)(bb + 256);                       // Etot

  edge_hist_kernel<<<NBLK, 256, 0, stream>>>(ei, F, E, Etot, NB, NBLK);
  scan_part_kernel<<<NBS, 256, 0, stream>>>(F, bsum, L);
  scan_bsum_kernel<<<1, 256, 0, stream>>>(bsum, bb, S, NBS, L);
  scan_apply_kernel<<<NBS, 256, 0, stream>>>(F, bb, S, L);
  edge_scatter_kernel<<<NBLK, 256, 0, stream>>>(ei, S, stag, E, Etot, NB, NBLK);
  bucket_build_kernel<<<NB, 256, 0, stream>>>(stag, S, NBLK, rowptr, csr_src, N);

  convT_w_kernel<<<(256 * KP0 + 255) / 256, 256, 0, stream>>>(W0, Wt0, IN_CH, KP0);
  convT_w_kernel<<<(256 * 256 + 255) / 256, 256, 0, stream>>>(W1, Wt1, HID, HID);
  convT_w_kernel<<<(256 * 256 + 255) / 256, 256, 0, stream>>>(W2, Wt2, HID, HID);

  int gblocks = Mp / 128;
  int ablocks = (N + 3) / 4;
  int fblocks = (N + 4 * FKG - 1) / (4 * FKG);

  // layer 0 (fp32 A, conv + logits fused)
  gemm_f32a<<<gblocks, 512, 0, stream>>>(x, Wt0, Htb, en_s, en_d, as0, ad0, N, IN_CH, KP0);
  gat_agg_kernel<<<ablocks, 256, 0, stream>>>(Htb, en_s, en_d, rowptr, csr_src, b0, hb0, 1, N);
  // layer 1
  gemm_bf16<<<gblocks, 512, 0, stream>>>(hb0, Wt1, Htb, en_s, en_d, as1, ad1, N, HID);
  gat_agg_kernel<<<ablocks, 256, 0, stream>>>(Htb, en_s, en_d, rowptr, csr_src, b1, hb1, 1, N);
  // layer 2
  gemm_bf16<<<gblocks, 512, 0, stream>>>(hb1, Wt2, Htb, en_s, en_d, as2, ad2, N, HID);
  gat_agg_kernel<<<ablocks, 256, 0, stream>>>(Htb, en_s, en_d, rowptr, csr_src, b2, hb2, 0, N);

  final_kernel<<<fblocks, 256, 0, stream>>>(hb0, hb1, hb2, Wf, bf, out, N);
}